// Round 4
// baseline (214.490 us; speedup 1.0000x reference)
//
#include <hip/hip_runtime.h>

// VectorQuantizer on MI355X (gfx950), fp32 — bit-mimics the numpy fp32 reference:
//   dist = np.sum(zf*zf,1,keepdims=True) + np.sum(cb*cb,1) - 2*np.matmul(zf,cb.T)
//   indices = np.argmin(dist, 1)
// numpy pairwise_sum(n=64): 8 accumulators, rounded products (no FMA), tree combine.
// sgemm dot: single accumulator, sequential k, FMA.
// All emulated ops use explicit __f*_rn intrinsics (no contraction/reassociation).

#define C_DIM   64
#define N_EMB   512
#define HW      4096                 // 64*64
#define N_PIX   (32 * HW)            // 131072
#define ZQ_OFF  1
#define IDX_OFF (1 + N_PIX * C_DIM)  // 1 + 8388608

__global__ __launch_bounds__(256) void vq_main(
    const float* __restrict__ z,
    const float* __restrict__ cb,
    float* __restrict__ out,
    float* __restrict__ ws)
{
    __shared__ float esum[N_EMB];   // b_j = np.sum(cb*cb, axis=1), numpy-exact
    __shared__ float wsum[4];

    // b_j with numpy pairwise_sum(n=64) semantics: 8 accs, rounded mul, tree.
    for (int j = threadIdx.x; j < N_EMB; j += 256) {
        const float* e = cb + j * C_DIM;
        float r[8];
        #pragma unroll
        for (int i = 0; i < 8; ++i) r[i] = __fmul_rn(e[i], e[i]);
        #pragma unroll
        for (int k = 8; k < 64; k += 8) {
            #pragma unroll
            for (int i = 0; i < 8; ++i)
                r[i] = __fadd_rn(r[i], __fmul_rn(e[k + i], e[k + i]));
        }
        esum[j] = __fadd_rn(
            __fadd_rn(__fadd_rn(r[0], r[1]), __fadd_rn(r[2], r[3])),
            __fadd_rn(__fadd_rn(r[4], r[5]), __fadd_rn(r[6], r[7])));
    }
    __syncthreads();

    const int p  = blockIdx.x * 256 + threadIdx.x;   // pixel id, coalesced
    const int b  = p >> 12;                          // batch
    const int hw = p & (HW - 1);                     // h*64+w
    const float* zp = z + (size_t)b * (C_DIM * HW) + hw;

    // z vector for this pixel (NHWC row order c=0..63): 64 f32 in VGPRs.
    float zr[C_DIM];
    #pragma unroll
    for (int c = 0; c < C_DIM; ++c) zr[c] = zp[(size_t)c * HW];

    // a_p = np.sum(zf*zf, axis=1) with the same numpy-exact pattern.
    float ap;
    {
        float r[8];
        #pragma unroll
        for (int i = 0; i < 8; ++i) r[i] = __fmul_rn(zr[i], zr[i]);
        #pragma unroll
        for (int k = 8; k < 64; k += 8) {
            #pragma unroll
            for (int i = 0; i < 8; ++i)
                r[i] = __fadd_rn(r[i], __fmul_rn(zr[k + i], zr[k + i]));
        }
        ap = __fadd_rn(
            __fadd_rn(__fadd_rn(r[0], r[1]), __fadd_rn(r[2], r[3])),
            __fadd_rn(__fadd_rn(r[4], r[5]), __fadd_rn(r[6], r[7])));
    }

    // Argmin over 512 codes, bit-mimicking the reference rounding:
    //   dot   = sequential FMA chain k=0..63 (sgemm microkernel order)
    //   dist  = fp32( fp32(ap + b_j) - fp32(2*dot) )
    // j is wave-uniform -> codebook reads scalarize to s_load (SGPR operands).
    float best = 3.0e38f;
    int   bj   = 0;
    #pragma unroll 2
    for (int j = 0; j < N_EMB; ++j) {
        const float* __restrict__ e = cb + j * C_DIM;
        float acc = 0.0f;
        #pragma unroll
        for (int c = 0; c < C_DIM; ++c)
            acc = __fmaf_rn(zr[c], e[c], acc);
        float d = __fsub_rn(__fadd_rn(ap, esum[j]), __fmul_rn(2.0f, acc));
        if (d < best) { best = d; bj = j; }   // strict '<' == np.argmin first-min
    }

    // Epilogue: gather winning code, write z_q in NCHW (coalesced per c-plane),
    // accumulate MSE partial.
    const float* __restrict__ eb = cb + bj * C_DIM;
    float* zq = out + ZQ_OFF + (size_t)b * (C_DIM * HW) + hw;
    float ls = 0.f;
    #pragma unroll
    for (int c = 0; c < C_DIM; ++c) {
        float ec = eb[c];
        zq[(size_t)c * HW] = ec;
        float df = ec - zr[c];
        ls = fmaf(df, df, ls);
    }
    out[IDX_OFF + p] = (float)bj;

    // Block-reduce loss partial -> ws[blockIdx.x] (deterministic).
    #pragma unroll
    for (int off = 32; off; off >>= 1) ls += __shfl_down(ls, off, 64);
    const int lane = threadIdx.x & 63, wid = threadIdx.x >> 6;
    if (lane == 0) wsum[wid] = ls;
    __syncthreads();
    if (threadIdx.x == 0)
        ws[blockIdx.x] = (wsum[0] + wsum[1]) + (wsum[2] + wsum[3]);
}

__global__ __launch_bounds__(256) void vq_loss(
    const float* __restrict__ ws, float* __restrict__ out)
{
    __shared__ float sm[4];
    float v = ws[threadIdx.x] + ws[threadIdx.x + 256];
    #pragma unroll
    for (int off = 32; off; off >>= 1) v += __shfl_down(v, off, 64);
    const int lane = threadIdx.x & 63, wid = threadIdx.x >> 6;
    if (lane == 0) sm[wid] = v;
    __syncthreads();
    if (threadIdx.x == 0)
        out[0] = ((sm[0] + sm[1]) + (sm[2] + sm[3])) * (1.0f / 8388608.0f);
}

extern "C" void kernel_launch(void* const* d_in, const int* in_sizes, int n_in,
                              void* d_out, int out_size, void* d_ws, size_t ws_size,
                              hipStream_t stream)
{
    const float* z  = (const float*)d_in[0];   // 8388608 f32
    const float* cb = (const float*)d_in[1];   // 32768 f32
    float* out = (float*)d_out;
    float* ws  = (float*)d_ws;                 // 512 f32 partials

    vq_main<<<N_PIX / 256, 256, 0, stream>>>(z, cb, out, ws);
    vq_loss<<<1, 256, 0, stream>>>(ws, out);
}

// Round 5
// 165.672 us; speedup vs baseline: 1.2947x; 1.2947x over previous
//
#include <hip/hip_runtime.h>

// VectorQuantizer on MI355X (gfx950), fp32 — bit-mimics the numpy fp32 reference.
// Round 4: keep numerics identical to round 3 (which passed); attack the 55%
// VALUBusy stall: (1) pin the 64-float z vector in VGPRs (VGPR_Count=44 proved
// the compiler was rematerializing z loads inside the 512-code loop),
// (2) stage the 128KB codebook in LDS in two 64KB halves (uniform-address
// ds_read broadcast, conflict-free) instead of sweeping global via scalar cache.

#define C_DIM   64
#define N_EMB   512
#define HALF    256                  // codes per LDS half
#define HW      4096                 // 64*64
#define N_PIX   (32 * HW)            // 131072
#define ZQ_OFF  1
#define IDX_OFF (1 + N_PIX * C_DIM)  // 1 + 8388608

__global__ __launch_bounds__(256, 2) void vq_main(
    const float* __restrict__ z,
    const float* __restrict__ cb,
    float* __restrict__ out,
    float* __restrict__ ws)
{
    __shared__ float4 ecb4[HALF * C_DIM / 4];  // 64KB: one half of the codebook
    __shared__ float  esum[N_EMB];             // b_j = np.sum(cb*cb,1), numpy-exact
    __shared__ float  wsum[4];

    // b_j with numpy pairwise_sum(n=64) semantics: 8 accs, rounded mul, tree.
    for (int j = threadIdx.x; j < N_EMB; j += 256) {
        const float* e = cb + j * C_DIM;
        float r[8];
        #pragma unroll
        for (int i = 0; i < 8; ++i) r[i] = __fmul_rn(e[i], e[i]);
        #pragma unroll
        for (int k = 8; k < 64; k += 8) {
            #pragma unroll
            for (int i = 0; i < 8; ++i)
                r[i] = __fadd_rn(r[i], __fmul_rn(e[k + i], e[k + i]));
        }
        esum[j] = __fadd_rn(
            __fadd_rn(__fadd_rn(r[0], r[1]), __fadd_rn(r[2], r[3])),
            __fadd_rn(__fadd_rn(r[4], r[5]), __fadd_rn(r[6], r[7])));
    }

    const int p  = blockIdx.x * 256 + threadIdx.x;   // pixel id, coalesced
    const int b  = p >> 12;                          // batch
    const int hw = p & (HW - 1);                     // h*64+w
    const float* zp = z + (size_t)b * (C_DIM * HW) + hw;

    // z vector for this pixel: 64 f32, PINNED in VGPRs (asm = opaque def, the
    // compiler cannot rematerialize the global loads past it).
    float zr[C_DIM];
    #pragma unroll
    for (int c = 0; c < C_DIM; ++c) zr[c] = zp[(size_t)c * HW];
    #pragma unroll
    for (int c = 0; c < C_DIM; ++c) asm volatile("" : "+v"(zr[c]));

    // a_p = np.sum(zf*zf, axis=1), numpy-exact pattern.
    float ap;
    {
        float r[8];
        #pragma unroll
        for (int i = 0; i < 8; ++i) r[i] = __fmul_rn(zr[i], zr[i]);
        #pragma unroll
        for (int k = 8; k < 64; k += 8) {
            #pragma unroll
            for (int i = 0; i < 8; ++i)
                r[i] = __fadd_rn(r[i], __fmul_rn(zr[k + i], zr[k + i]));
        }
        ap = __fadd_rn(
            __fadd_rn(__fadd_rn(r[0], r[1]), __fadd_rn(r[2], r[3])),
            __fadd_rn(__fadd_rn(r[4], r[5]), __fadd_rn(r[6], r[7])));
    }

    // Argmin over 512 codes in two LDS-staged halves of 256.
    //   dot  = sequential FMA chain c=0..63 (sgemm order, bit-exact)
    //   dist = fp32( fp32(ap + b_j) - fp32(2*dot) )
    float best = 3.0e38f;
    int   bj   = 0;
    for (int h = 0; h < 2; ++h) {
        __syncthreads();   // all waves done with previous half / esum written
        {   // stage 64KB: 4096 float4, 16 per thread, coalesced
            const float4* src = (const float4*)(cb + h * (HALF * C_DIM));
            #pragma unroll
            for (int i = 0; i < 16; ++i)
                ecb4[threadIdx.x + i * 256] = src[threadIdx.x + i * 256];
        }
        __syncthreads();

        const float* __restrict__ eb0 = (const float*)ecb4;
        #pragma unroll 2
        for (int jj = 0; jj < HALF; ++jj) {
            const int j = h * HALF + jj;
            const float* __restrict__ e = eb0 + jj * C_DIM;  // uniform addr -> broadcast
            float acc = 0.0f;
            #pragma unroll
            for (int c = 0; c < C_DIM; ++c)
                acc = __fmaf_rn(zr[c], e[c], acc);
            float d = __fsub_rn(__fadd_rn(ap, esum[j]), __fmul_rn(2.0f, acc));
            if (d < best) { best = d; bj = j; }   // strict '<' == np first-min
        }
    }

    // Epilogue: gather winning code (L2-resident), write z_q in NCHW
    // (coalesced per c-plane), accumulate MSE partial.
    const float* __restrict__ ebw = cb + bj * C_DIM;
    float* zq = out + ZQ_OFF + (size_t)b * (C_DIM * HW) + hw;
    float ls = 0.f;
    #pragma unroll
    for (int c = 0; c < C_DIM; ++c) {
        float ec = ebw[c];
        zq[(size_t)c * HW] = ec;
        float df = ec - zr[c];
        ls = fmaf(df, df, ls);
    }
    out[IDX_OFF + p] = (float)bj;

    // Block-reduce loss partial -> ws[blockIdx.x] (deterministic).
    #pragma unroll
    for (int off = 32; off; off >>= 1) ls += __shfl_down(ls, off, 64);
    const int lane = threadIdx.x & 63, wid = threadIdx.x >> 6;
    if (lane == 0) wsum[wid] = ls;
    __syncthreads();
    if (threadIdx.x == 0)
        ws[blockIdx.x] = (wsum[0] + wsum[1]) + (wsum[2] + wsum[3]);
}

__global__ __launch_bounds__(256) void vq_loss(
    const float* __restrict__ ws, float* __restrict__ out)
{
    __shared__ float sm[4];
    float v = ws[threadIdx.x] + ws[threadIdx.x + 256];
    #pragma unroll
    for (int off = 32; off; off >>= 1) v += __shfl_down(v, off, 64);
    const int lane = threadIdx.x & 63, wid = threadIdx.x >> 6;
    if (lane == 0) sm[wid] = v;
    __syncthreads();
    if (threadIdx.x == 0)
        out[0] = ((sm[0] + sm[1]) + (sm[2] + sm[3])) * (1.0f / 8388608.0f);
}

extern "C" void kernel_launch(void* const* d_in, const int* in_sizes, int n_in,
                              void* d_out, int out_size, void* d_ws, size_t ws_size,
                              hipStream_t stream)
{
    const float* z  = (const float*)d_in[0];   // 8388608 f32
    const float* cb = (const float*)d_in[1];   // 32768 f32
    float* out = (float*)d_out;
    float* ws  = (float*)d_ws;                 // 512 f32 partials

    vq_main<<<N_PIX / 256, 256, 0, stream>>>(z, cb, out, ws);
    vq_loss<<<1, 256, 0, stream>>>(ws, out);
}